// Round 1
// 596.392 us; speedup vs baseline: 1.1523x; 1.1523x over previous
//
#include <hip/hip_runtime.h>
#include <hip/hip_bf16.h>
#include <stdint.h>

// Problem constants (fixed by the reference setup_inputs)
#define BATCH 8
#define C 64
#define C3 192
#define HW 65536            // 256*256
#define NPIX (BATCH * HW)   // 524288 pixels total

typedef unsigned short u16;

typedef __bf16 bf16x8 __attribute__((ext_vector_type(8)));
typedef float f32x4 __attribute__((ext_vector_type(4)));

union FragU {
  bf16x8 v;
  u16 u[8];
  uint4 q;
};

// bf16 (as raw u16) -> f32 : exact
__device__ __forceinline__ float bf2f(unsigned int u) {
  return __uint_as_float(u << 16);
}
// f32 -> bf16 raw bits, round-to-nearest-even
__device__ __forceinline__ u16 f2bf(float f) {
  unsigned int x = __float_as_uint(f);
  unsigned int r = (x + 0x7fffu + ((x >> 16) & 1u)) >> 16;
  return (u16)r;
}

__device__ __forceinline__ void unpack8(uint4 v, float* f) {
  f[0] = bf2f(v.x & 0xffffu); f[1] = bf2f(v.x >> 16);
  f[2] = bf2f(v.y & 0xffffu); f[3] = bf2f(v.y >> 16);
  f[4] = bf2f(v.z & 0xffffu); f[5] = bf2f(v.z >> 16);
  f[6] = bf2f(v.w & 0xffffu); f[7] = bf2f(v.w >> 16);
}

// ---------------------------------------------------------------------------
// K0: input-dtype sniffer (bf16 vs fp32).
// flag = 1 -> inputs are bf16 ; flag = 0 -> inputs are fp32.
// ---------------------------------------------------------------------------
__global__ void k0_det(const unsigned int* __restrict__ xbits,
                       int* __restrict__ flag) {
  __shared__ int cnt;
  if (threadIdx.x == 0) cnt = 0;
  __syncthreads();
  unsigned int u = xbits[threadIdx.x];
  int e = (u >> 7) & 0xff;  // exponent of low-half-as-bf16
  int pred = (e >= 96 && e <= 134) ? 1 : 0;
  atomicAdd(&cnt, pred);
  __syncthreads();
  if (threadIdx.x == 0) *flag = (cnt >= 128) ? 1 : 0;
}

// ---------------------------------------------------------------------------
// K1 (MFMA): 1x1 conv as GEMM  qkv1[co,px] = sum_ci W[co,ci] * x[ci,px].
// Block: 256 threads (4 waves), BN=256 px (one n-plane slice), BM=192, K=64.
// W staged to LDS as bf16 with XOR swizzle (byte ^= (row&7)<<4) -> conflict-
// free ds_read_b128 A-fragments. B-fragments loaded directly from global
// (each x element read by exactly one block), converted to bf16 in-flight.
// Per wave: 64 px, 4 M-chunks of 48 co, 96 MFMAs (16x16x32 bf16).
// grid = NPIX/256 = 2048 blocks.
// ---------------------------------------------------------------------------
__global__ __launch_bounds__(256) void k1_mfma(const void* __restrict__ xv,
                                               const void* __restrict__ wv,
                                               u16* __restrict__ qkv1,
                                               const int* __restrict__ flag) {
  const int isbf = *flag;  // uniform branch
  __shared__ u16 wl[C3 * C];  // 24576 B, swizzled bf16 weights
  for (int i = threadIdx.x; i < C3 * C; i += 256) {
    int row = i >> 6, col = i & 63;
    u16 b = isbf ? ((const u16*)wv)[i] : f2bf(((const float*)wv)[i]);
    int byt = row * 128 + ((col * 2) ^ ((row & 7) << 4));
    *(u16*)((char*)wl + byt) = b;
  }
  __syncthreads();

  const int w = threadIdx.x >> 6;
  const int l = threadIdx.x & 63;
  const int lg = l >> 4;   // lane group 0..3
  const int lr = l & 15;   // lane row/col 0..15
  const int n = blockIdx.x >> 8;                       // image index
  const int hwbase = ((blockIdx.x & 255) << 8) + w * 64 + lr;

  // ---- B fragments [nt][ks]: B[k][px], k = ks*32 + lg*8 + e, px = hwbase+nt*16
  FragU bfr[4][2];
  if (isbf) {
    const u16* xp = (const u16*)xv + (((size_t)n * C) << 16);
#pragma unroll
    for (int nt = 0; nt < 4; ++nt)
#pragma unroll
      for (int ks = 0; ks < 2; ++ks) {
        const u16* p = xp + (((size_t)(ks * 32 + lg * 8)) << 16) + hwbase + nt * 16;
#pragma unroll
        for (int e = 0; e < 8; ++e) bfr[nt][ks].u[e] = p[(size_t)e << 16];
      }
  } else {
    const float* xp = (const float*)xv + (((size_t)n * C) << 16);
#pragma unroll
    for (int nt = 0; nt < 4; ++nt)
#pragma unroll
      for (int ks = 0; ks < 2; ++ks) {
        const float* p = xp + (((size_t)(ks * 32 + lg * 8)) << 16) + hwbase + nt * 16;
#pragma unroll
        for (int e = 0; e < 8; ++e) bfr[nt][ks].u[e] = f2bf(p[(size_t)e << 16]);
      }
  }

  // ---- M-chunk loop: 48 output channels per chunk
#pragma unroll
  for (int mc = 0; mc < 4; ++mc) {
    bf16x8 af[3][2];
#pragma unroll
    for (int mt = 0; mt < 3; ++mt)
#pragma unroll
      for (int ks = 0; ks < 2; ++ks) {
        int row = mc * 48 + mt * 16 + lr;     // A row (co)
        int colb = ks * 64 + lg * 16;         // byte offset of k-slice
        FragU a;
        a.q = *(const uint4*)((const char*)wl + row * 128 +
                              (colb ^ ((row & 7) << 4)));
        af[mt][ks] = a.v;
      }
#pragma unroll
    for (int mt = 0; mt < 3; ++mt) {
#pragma unroll
      for (int nt = 0; nt < 4; ++nt) {
        f32x4 acc = {0.f, 0.f, 0.f, 0.f};
        acc = __builtin_amdgcn_mfma_f32_16x16x32_bf16(af[mt][0], bfr[nt][0].v,
                                                      acc, 0, 0, 0);
        acc = __builtin_amdgcn_mfma_f32_16x16x32_bf16(af[mt][1], bfr[nt][1].v,
                                                      acc, 0, 0, 0);
        int co = mc * 48 + mt * 16 + lg * 4;  // D row = lg*4 + r
        u16* op = qkv1 + (((size_t)(n * C3 + co)) << 16) + hwbase + nt * 16;
#pragma unroll
        for (int r = 0; r < 4; ++r) op[(size_t)r << 16] = f2bf(acc[r]);
      }
    }
  }
}

// ---------------------------------------------------------------------------
// K2: 3x3 depthwise conv, SAME zero padding, groups=192. (unchanged)
// ---------------------------------------------------------------------------
__global__ __launch_bounds__(256) void k2_dw(const u16* __restrict__ qkv1,
                                             const void* __restrict__ dwv,
                                             u16* __restrict__ qkv2,
                                             const int* __restrict__ flag) {
  const int isbf = *flag;
  unsigned int gg = blockIdx.x * 256 + threadIdx.x;  // group id < 12582912
  int nc = (int)(gg >> 13);         // 8192 groups of 8 per plane
  int rem = (int)(gg & 8191);
  int h = rem >> 5;                 // 32 groups per row
  int col0 = (rem & 31) * 8;
  int ch = nc % C3;

  float wv[9];
  if (isbf) {
    const u16* dw = (const u16*)dwv;
#pragma unroll
    for (int t = 0; t < 9; ++t) wv[t] = bf2f(dw[ch * 9 + t]);
  } else {
    const float* dw = (const float*)dwv;
#pragma unroll
    for (int t = 0; t < 9; ++t) wv[t] = dw[ch * 9 + t];
  }

  const u16* base = qkv1 + ((size_t)nc << 16);
  float acc[8];
#pragma unroll
  for (int j = 0; j < 8; ++j) acc[j] = 0.f;

#pragma unroll
  for (int kh = 0; kh < 3; ++kh) {
    int hh = h + kh - 1;
    if (hh < 0 || hh > 255) continue;
    const u16* rp = base + hh * 256 + col0;
    uint4 rv = *reinterpret_cast<const uint4*>(rp);
    float r[8];
    unpack8(rv, r);
    float lft = (col0 > 0) ? bf2f(rp[-1]) : 0.f;
    float rgt = (col0 < 248) ? bf2f(rp[8]) : 0.f;
    float w0 = wv[kh * 3], w1 = wv[kh * 3 + 1], w2 = wv[kh * 3 + 2];
    acc[0] += lft * w0 + r[0] * w1 + r[1] * w2;
#pragma unroll
    for (int j = 1; j < 7; ++j)
      acc[j] += r[j - 1] * w0 + r[j] * w1 + r[j + 1] * w2;
    acc[7] += r[6] * w0 + r[7] * w1 + rgt * w2;
  }

  unsigned int pk[4];
#pragma unroll
  for (int jj = 0; jj < 4; ++jj) {
    u16 lo = f2bf(acc[jj * 2]);
    u16 hi = f2bf(acc[jj * 2 + 1]);
    pk[jj] = (unsigned int)lo | ((unsigned int)hi << 16);
  }
  *reinterpret_cast<uint4*>(qkv2 + ((size_t)nc << 16) + h * 256 + col0) =
      make_uint4(pk[0], pk[1], pk[2], pk[3]);
}

// ---------------------------------------------------------------------------
// K3: per-(n,c,patch) 8x8 circular convolution (== irfft2(rfft2(q)*rfft2(k))),
// times temperature[c], times v.  One thread per channel-patch.
// CHANGED: output bf16 (numerically identical to fp32-out + bf16 round in K4).
// grid = B*C*32*32/256 = 2048 blocks.
// ---------------------------------------------------------------------------
__global__ __launch_bounds__(256) void k3_attn(const u16* __restrict__ qkv2,
                                               const void* __restrict__ tv,
                                               u16* __restrict__ voutb,
                                               const int* __restrict__ flag) {
  const int isbf = *flag;
  unsigned int g = blockIdx.x * 256 + threadIdx.x;  // < 524288
  int pw = g & 31;
  int ph = (g >> 5) & 31;
  int c = (g >> 10) & 63;
  int n = g >> 16;

  size_t pofs = (size_t)ph * (8 * 256) + (size_t)pw * 8;
  const u16* qp = qkv2 + (((size_t)(n * C3 + c)) << 16) + pofs;
  const u16* kp = qp + ((size_t)C << 16);
  const u16* vp = qp + ((size_t)(2 * C) << 16);

  float kreg[64];
#pragma unroll
  for (int r = 0; r < 8; ++r) {
    uint4 kv = *reinterpret_cast<const uint4*>(kp + r * 256);
    unpack8(kv, &kreg[r * 8]);
  }
  float acc[64];
#pragma unroll
  for (int i = 0; i < 64; ++i) acc[i] = 0.f;

#pragma unroll
  for (int a = 0; a < 8; ++a) {
    uint4 qv4 = *reinterpret_cast<const uint4*>(qp + a * 256);
    float qrow[8];
    unpack8(qv4, qrow);
#pragma unroll
    for (int b = 0; b < 8; ++b) {
      float qv = qrow[b];
#pragma unroll
      for (int i = 0; i < 8; ++i) {
#pragma unroll
        for (int j = 0; j < 8; ++j) {
          acc[i * 8 + j] += qv * kreg[((i - a) & 7) * 8 + ((j - b) & 7)];
        }
      }
    }
  }

  float tc = isbf ? bf2f(((const u16*)tv)[c]) : ((const float*)tv)[c];
  u16* op = voutb + (((size_t)(n * C + c)) << 16) + pofs;
#pragma unroll
  for (int i = 0; i < 8; ++i) {
    uint4 vv4 = *reinterpret_cast<const uint4*>(vp + i * 256);
    float vrow[8];
    unpack8(vv4, vrow);
    unsigned int pk[4];
#pragma unroll
    for (int jj = 0; jj < 4; ++jj) {
      u16 lo = f2bf(acc[i * 8 + jj * 2] * tc * vrow[jj * 2]);
      u16 hi = f2bf(acc[i * 8 + jj * 2 + 1] * tc * vrow[jj * 2 + 1]);
      pk[jj] = (unsigned int)lo | ((unsigned int)hi << 16);
    }
    *reinterpret_cast<uint4*>(op + i * 256) = make_uint4(pk[0], pk[1], pk[2], pk[3]);
  }
}

// ---------------------------------------------------------------------------
// K4 (MFMA): 1x1 proj conv as GEMM  out[co,px] = sum_ci Wp[co,ci]*vout[ci,px].
// vin is bf16 (written by K3). Output fp32. Same template as K1 with M=64.
// grid = 2048 blocks.
// ---------------------------------------------------------------------------
__global__ __launch_bounds__(256) void k4_mfma(const u16* __restrict__ vin,
                                               const void* __restrict__ pwv,
                                               float* __restrict__ outp,
                                               const int* __restrict__ flag) {
  const int isbf = *flag;
  __shared__ u16 wl[C * C];  // 8192 B, swizzled bf16 weights
  for (int i = threadIdx.x; i < C * C; i += 256) {
    int row = i >> 6, col = i & 63;
    u16 b = isbf ? ((const u16*)pwv)[i] : f2bf(((const float*)pwv)[i]);
    *(u16*)((char*)wl + row * 128 + ((col * 2) ^ ((row & 7) << 4))) = b;
  }
  __syncthreads();

  const int w = threadIdx.x >> 6;
  const int l = threadIdx.x & 63;
  const int lg = l >> 4, lr = l & 15;
  const int n = blockIdx.x >> 8;
  const int hwbase = ((blockIdx.x & 255) << 8) + w * 64 + lr;

  const u16* xp = vin + (((size_t)n * C) << 16);
  FragU bfr[4][2];
#pragma unroll
  for (int nt = 0; nt < 4; ++nt)
#pragma unroll
    for (int ks = 0; ks < 2; ++ks) {
      const u16* p = xp + (((size_t)(ks * 32 + lg * 8)) << 16) + hwbase + nt * 16;
#pragma unroll
      for (int e = 0; e < 8; ++e) bfr[nt][ks].u[e] = p[(size_t)e << 16];
    }

#pragma unroll
  for (int mt = 0; mt < 4; ++mt) {
    bf16x8 af[2];
#pragma unroll
    for (int ks = 0; ks < 2; ++ks) {
      int row = mt * 16 + lr;
      int colb = ks * 64 + lg * 16;
      FragU a;
      a.q = *(const uint4*)((const char*)wl + row * 128 +
                            (colb ^ ((row & 7) << 4)));
      af[ks] = a.v;
    }
#pragma unroll
    for (int nt = 0; nt < 4; ++nt) {
      f32x4 acc = {0.f, 0.f, 0.f, 0.f};
      acc = __builtin_amdgcn_mfma_f32_16x16x32_bf16(af[0], bfr[nt][0].v, acc, 0, 0, 0);
      acc = __builtin_amdgcn_mfma_f32_16x16x32_bf16(af[1], bfr[nt][1].v, acc, 0, 0, 0);
      int co = mt * 16 + lg * 4;
      float* op = outp + (((size_t)(n * C + co)) << 16) + hwbase + nt * 16;
#pragma unroll
      for (int r = 0; r < 4; ++r) op[(size_t)r << 16] = acc[r];
    }
  }
}

// ---------------------------------------------------------------------------
extern "C" void kernel_launch(void* const* d_in, const int* in_sizes, int n_in,
                              void* d_out, int out_size, void* d_ws, size_t ws_size,
                              hipStream_t stream) {
  const void* x = d_in[0];       // (8,64,256,256)   bf16 or fp32
  const void* qkv_w = d_in[1];   // (192,64,1,1)
  const void* dw_w = d_in[2];    // (192,1,3,3)
  const void* proj_w = d_in[3];  // (64,64,1,1)
  const void* temp = d_in[4];    // (64,1,1)

  // workspace layout:
  //   qkv1 bf16 [B,192,H,W] : bytes [0, 201326592)
  //   qkv2 bf16 [B,192,H,W] : bytes [201326592, 402653184)
  //   voutb bf16 [B,64,H,W] : reuses bytes [0, 67108864) (qkv1 dead after K2)
  //   flag int              : byte 402653184
  u16* qkv1 = (u16*)d_ws;
  u16* qkv2 = qkv1 + (size_t)BATCH * C3 * HW;
  u16* voutb = (u16*)d_ws;
  int* flag = (int*)((char*)d_ws + (size_t)2 * BATCH * C3 * HW * 2);
  float* outp = (float*)d_out;

  k0_det<<<1, 256, 0, stream>>>((const unsigned int*)x, flag);
  k1_mfma<<<NPIX / 256, 256, 0, stream>>>(x, qkv_w, qkv1, flag);
  k2_dw<<<(BATCH * C3 * HW) / 8 / 256, 256, 0, stream>>>(qkv1, dw_w, qkv2, flag);
  k3_attn<<<NPIX / 256, 256, 0, stream>>>(qkv2, temp, voutb, flag);
  k4_mfma<<<NPIX / 256, 256, 0, stream>>>(voutb, proj_w, outp, flag);
}

// Round 2
// 533.244 us; speedup vs baseline: 1.2888x; 1.1184x over previous
//
#include <hip/hip_runtime.h>
#include <hip/hip_bf16.h>
#include <stdint.h>

// Problem constants (fixed by the reference setup_inputs)
#define BATCH 8
#define C 64
#define C3 192
#define HW 65536            // 256*256
#define NPIX (BATCH * HW)   // 524288 pixels total

typedef unsigned short u16;

typedef __bf16 bf16x8 __attribute__((ext_vector_type(8)));
typedef float f32x4 __attribute__((ext_vector_type(4)));

union FragU {
  bf16x8 v;
  u16 u[8];
  uint4 q;
};

// bf16 (as raw u16) -> f32 : exact
__device__ __forceinline__ float bf2f(unsigned int u) {
  return __uint_as_float(u << 16);
}
// f32 -> bf16 raw bits, round-to-nearest-even
__device__ __forceinline__ u16 f2bf(float f) {
  unsigned int x = __float_as_uint(f);
  unsigned int r = (x + 0x7fffu + ((x >> 16) & 1u)) >> 16;
  return (u16)r;
}

__device__ __forceinline__ void unpack8(uint4 v, float* f) {
  f[0] = bf2f(v.x & 0xffffu); f[1] = bf2f(v.x >> 16);
  f[2] = bf2f(v.y & 0xffffu); f[3] = bf2f(v.y >> 16);
  f[4] = bf2f(v.z & 0xffffu); f[5] = bf2f(v.z >> 16);
  f[6] = bf2f(v.w & 0xffffu); f[7] = bf2f(v.w >> 16);
}

// ---------------------------------------------------------------------------
// K0: input-dtype sniffer (bf16 vs fp32).
// flag = 1 -> inputs are bf16 ; flag = 0 -> inputs are fp32.
// ---------------------------------------------------------------------------
__global__ void k0_det(const unsigned int* __restrict__ xbits,
                       int* __restrict__ flag) {
  __shared__ int cnt;
  if (threadIdx.x == 0) cnt = 0;
  __syncthreads();
  unsigned int u = xbits[threadIdx.x];
  int e = (u >> 7) & 0xff;  // exponent of low-half-as-bf16
  int pred = (e >= 96 && e <= 134) ? 1 : 0;
  atomicAdd(&cnt, pred);
  __syncthreads();
  if (threadIdx.x == 0) *flag = (cnt >= 128) ? 1 : 0;
}

// ---------------------------------------------------------------------------
// K1 (MFMA): 1x1 conv as GEMM  qkv1[co,px] = sum_ci W[co,ci] * x[ci,px].
// Block: 256 threads (4 waves), BN=256 px, BM=192, K=64. (unchanged)
// ---------------------------------------------------------------------------
__global__ __launch_bounds__(256) void k1_mfma(const void* __restrict__ xv,
                                               const void* __restrict__ wv,
                                               u16* __restrict__ qkv1,
                                               const int* __restrict__ flag) {
  const int isbf = *flag;  // uniform branch
  __shared__ u16 wl[C3 * C];  // 24576 B, swizzled bf16 weights
  for (int i = threadIdx.x; i < C3 * C; i += 256) {
    int row = i >> 6, col = i & 63;
    u16 b = isbf ? ((const u16*)wv)[i] : f2bf(((const float*)wv)[i]);
    int byt = row * 128 + ((col * 2) ^ ((row & 7) << 4));
    *(u16*)((char*)wl + byt) = b;
  }
  __syncthreads();

  const int w = threadIdx.x >> 6;
  const int l = threadIdx.x & 63;
  const int lg = l >> 4;   // lane group 0..3
  const int lr = l & 15;   // lane row/col 0..15
  const int n = blockIdx.x >> 8;                       // image index
  const int hwbase = ((blockIdx.x & 255) << 8) + w * 64 + lr;

  // ---- B fragments [nt][ks]: B[k][px], k = ks*32 + lg*8 + e, px = hwbase+nt*16
  FragU bfr[4][2];
  if (isbf) {
    const u16* xp = (const u16*)xv + (((size_t)n * C) << 16);
#pragma unroll
    for (int nt = 0; nt < 4; ++nt)
#pragma unroll
      for (int ks = 0; ks < 2; ++ks) {
        const u16* p = xp + (((size_t)(ks * 32 + lg * 8)) << 16) + hwbase + nt * 16;
#pragma unroll
        for (int e = 0; e < 8; ++e) bfr[nt][ks].u[e] = p[(size_t)e << 16];
      }
  } else {
    const float* xp = (const float*)xv + (((size_t)n * C) << 16);
#pragma unroll
    for (int nt = 0; nt < 4; ++nt)
#pragma unroll
      for (int ks = 0; ks < 2; ++ks) {
        const float* p = xp + (((size_t)(ks * 32 + lg * 8)) << 16) + hwbase + nt * 16;
#pragma unroll
        for (int e = 0; e < 8; ++e) bfr[nt][ks].u[e] = f2bf(p[(size_t)e << 16]);
      }
  }

  // ---- M-chunk loop: 48 output channels per chunk
#pragma unroll
  for (int mc = 0; mc < 4; ++mc) {
    bf16x8 af[3][2];
#pragma unroll
    for (int mt = 0; mt < 3; ++mt)
#pragma unroll
      for (int ks = 0; ks < 2; ++ks) {
        int row = mc * 48 + mt * 16 + lr;     // A row (co)
        int colb = ks * 64 + lg * 16;         // byte offset of k-slice
        FragU a;
        a.q = *(const uint4*)((const char*)wl + row * 128 +
                              (colb ^ ((row & 7) << 4)));
        af[mt][ks] = a.v;
      }
#pragma unroll
    for (int mt = 0; mt < 3; ++mt) {
#pragma unroll
      for (int nt = 0; nt < 4; ++nt) {
        f32x4 acc = {0.f, 0.f, 0.f, 0.f};
        acc = __builtin_amdgcn_mfma_f32_16x16x32_bf16(af[mt][0], bfr[nt][0].v,
                                                      acc, 0, 0, 0);
        acc = __builtin_amdgcn_mfma_f32_16x16x32_bf16(af[mt][1], bfr[nt][1].v,
                                                      acc, 0, 0, 0);
        int co = mc * 48 + mt * 16 + lg * 4;  // D row = lg*4 + r
        u16* op = qkv1 + (((size_t)(n * C3 + co)) << 16) + hwbase + nt * 16;
#pragma unroll
        for (int r = 0; r < 4; ++r) op[(size_t)r << 16] = f2bf(acc[r]);
      }
    }
  }
}

// ---------------------------------------------------------------------------
// K23 (fused): 3x3 depthwise conv + 8x8 patch circular-correlation attention.
// Block = one (n, c) channel-triple and an 8-row x 256-col strip (= exactly
// one patch row, 32 patches). 256 threads, 4 waves.
//   Phase 1: stage 10x256 halo rows of q/k/v planes of qkv1 (bf16) to LDS.
//   Phase 2: depthwise 3x3 conv -> dw_s[pl] f32, PATCH-MAJOR [p][a][b] with
//            patch stride 65 (odd) so all phase-3 access patterns hit
//            <=2-way bank aliasing (free on CDNA4).
//   Phase 3: out[s][j] = sum_{a,b} q[a][b]*k[(s-a)&7][(j-b)&7]; multiply by
//            temperature[c] * v[s][j]; pack 8 bf16 -> one uint4 store.
// Eliminates the 402 MB qkv2 round-trip entirely.
// grid = 8*64*32 = 16384 blocks.
// ---------------------------------------------------------------------------
__global__ __launch_bounds__(256) void k23_fused(const u16* __restrict__ qkv1,
                                                 const void* __restrict__ dwv,
                                                 const void* __restrict__ tv,
                                                 u16* __restrict__ voutb,
                                                 const int* __restrict__ flag) {
  const int isbf = *flag;
  const int strip = blockIdx.x & 31;
  const int c = (blockIdx.x >> 5) & 63;
  const int n = blockIdx.x >> 11;
  const int h0 = strip * 8;
  const int tid = threadIdx.x;

  __shared__ u16 in_s[3][10 * 256];     // 15360 B  (bf16 staging, rows h0-1..h0+8)
  __shared__ float dw_s[3][32 * 65];    // 24960 B  (f32 dw outputs, patch-major)

  // ---- Phase 1: stage (coalesced uint4 rows; zero for out-of-image rows)
  for (int idx = tid; idx < 3 * 10 * 32; idx += 256) {
    int pl = idx / 320;
    int rem = idx - pl * 320;
    int r = rem >> 5;        // staged row 0..9  (global row h0 + r - 1)
    int cg = rem & 31;       // col group of 8
    int gh = h0 + r - 1;
    uint4 val = make_uint4(0u, 0u, 0u, 0u);
    if (gh >= 0 && gh < 256) {
      const u16* src = qkv1 + (((size_t)(n * C3 + c + 64 * pl)) << 16) +
                       gh * 256 + cg * 8;
      val = *reinterpret_cast<const uint4*>(src);
    }
    *reinterpret_cast<uint4*>(&in_s[pl][r * 256 + cg * 8]) = val;
  }
  __syncthreads();

  // ---- Phase 2: depthwise conv. thread -> (row = tid>>5, patch = tid&31)
  const int row = tid >> 5;   // output row within strip, 0..7
  const int pch = tid & 31;   // patch index == col group of 8
  const int col0 = pch * 8;

  for (int pl = 0; pl < 3; ++pl) {
    int ch = c + 64 * pl;
    float wv9[9];
    if (isbf) {
      const u16* dw = (const u16*)dwv;
#pragma unroll
      for (int t = 0; t < 9; ++t) wv9[t] = bf2f(dw[ch * 9 + t]);
    } else {
      const float* dw = (const float*)dwv;
#pragma unroll
      for (int t = 0; t < 9; ++t) wv9[t] = dw[ch * 9 + t];
    }
    float acc[8];
#pragma unroll
    for (int j = 0; j < 8; ++j) acc[j] = 0.f;
    // input center row for output row i is staged row i+1 -> rows i..i+2
#pragma unroll
    for (int kh = 0; kh < 3; ++kh) {
      const u16* rp = &in_s[pl][(row + kh) * 256 + col0];
      uint4 rv = *reinterpret_cast<const uint4*>(rp);
      float r8[8];
      unpack8(rv, r8);
      float lft = (col0 > 0) ? bf2f(rp[-1]) : 0.f;
      float rgt = (col0 < 248) ? bf2f(rp[8]) : 0.f;
      float w0 = wv9[kh * 3], w1 = wv9[kh * 3 + 1], w2 = wv9[kh * 3 + 2];
      acc[0] += lft * w0 + r8[0] * w1 + r8[1] * w2;
#pragma unroll
      for (int j = 1; j < 7; ++j)
        acc[j] += r8[j - 1] * w0 + r8[j] * w1 + r8[j + 1] * w2;
      acc[7] += r8[6] * w0 + r8[7] * w1 + rgt * w2;
    }
#pragma unroll
    for (int j = 0; j < 8; ++j) dw_s[pl][pch * 65 + row * 8 + j] = acc[j];
  }
  __syncthreads();

  // ---- Phase 3: 8x8 circular correlation, x temperature, x v
  const int s = row;  // this thread computes output row s of patch pch
  float acc8[8];
#pragma unroll
  for (int j = 0; j < 8; ++j) acc8[j] = 0.f;
  const float* qb = &dw_s[0][pch * 65];
  const float* kb = &dw_s[1][pch * 65];
#pragma unroll
  for (int a = 0; a < 8; ++a) {
    int kr = (s - a) & 7;          // runtime LDS row (addr math, not array idx)
    float krow[8];
#pragma unroll
    for (int e = 0; e < 8; ++e) krow[e] = kb[kr * 8 + e];
#pragma unroll
    for (int b = 0; b < 8; ++b) {
      float qab = qb[a * 8 + b];
#pragma unroll
      for (int j = 0; j < 8; ++j) acc8[j] += qab * krow[(j - b) & 7];
    }
  }

  float tc = isbf ? bf2f(((const u16*)tv)[c]) : ((const float*)tv)[c];
  const float* vb = &dw_s[2][pch * 65 + s * 8];
  unsigned int pk[4];
#pragma unroll
  for (int jj = 0; jj < 4; ++jj) {
    u16 lo = f2bf(acc8[jj * 2] * tc * vb[jj * 2]);
    u16 hi = f2bf(acc8[jj * 2 + 1] * tc * vb[jj * 2 + 1]);
    pk[jj] = (unsigned int)lo | ((unsigned int)hi << 16);
  }
  *reinterpret_cast<uint4*>(voutb + (((size_t)(n * C + c)) << 16) +
                            (h0 + s) * 256 + pch * 8) =
      make_uint4(pk[0], pk[1], pk[2], pk[3]);
}

// ---------------------------------------------------------------------------
// K4 (MFMA): 1x1 proj conv as GEMM  out[co,px] = sum_ci Wp[co,ci]*vout[ci,px].
// vin is bf16 (written by K23). Output fp32. (unchanged)
// ---------------------------------------------------------------------------
__global__ __launch_bounds__(256) void k4_mfma(const u16* __restrict__ vin,
                                               const void* __restrict__ pwv,
                                               float* __restrict__ outp,
                                               const int* __restrict__ flag) {
  const int isbf = *flag;
  __shared__ u16 wl[C * C];  // 8192 B, swizzled bf16 weights
  for (int i = threadIdx.x; i < C * C; i += 256) {
    int row = i >> 6, col = i & 63;
    u16 b = isbf ? ((const u16*)pwv)[i] : f2bf(((const float*)pwv)[i]);
    *(u16*)((char*)wl + row * 128 + ((col * 2) ^ ((row & 7) << 4))) = b;
  }
  __syncthreads();

  const int w = threadIdx.x >> 6;
  const int l = threadIdx.x & 63;
  const int lg = l >> 4, lr = l & 15;
  const int n = blockIdx.x >> 8;
  const int hwbase = ((blockIdx.x & 255) << 8) + w * 64 + lr;

  const u16* xp = vin + (((size_t)n * C) << 16);
  FragU bfr[4][2];
#pragma unroll
  for (int nt = 0; nt < 4; ++nt)
#pragma unroll
    for (int ks = 0; ks < 2; ++ks) {
      const u16* p = xp + (((size_t)(ks * 32 + lg * 8)) << 16) + hwbase + nt * 16;
#pragma unroll
      for (int e = 0; e < 8; ++e) bfr[nt][ks].u[e] = p[(size_t)e << 16];
    }

#pragma unroll
  for (int mt = 0; mt < 4; ++mt) {
    bf16x8 af[2];
#pragma unroll
    for (int ks = 0; ks < 2; ++ks) {
      int row = mt * 16 + lr;
      int colb = ks * 64 + lg * 16;
      FragU a;
      a.q = *(const uint4*)((const char*)wl + row * 128 +
                            (colb ^ ((row & 7) << 4)));
      af[ks] = a.v;
    }
#pragma unroll
    for (int nt = 0; nt < 4; ++nt) {
      f32x4 acc = {0.f, 0.f, 0.f, 0.f};
      acc = __builtin_amdgcn_mfma_f32_16x16x32_bf16(af[0], bfr[nt][0].v, acc, 0, 0, 0);
      acc = __builtin_amdgcn_mfma_f32_16x16x32_bf16(af[1], bfr[nt][1].v, acc, 0, 0, 0);
      int co = mt * 16 + lg * 4;
      float* op = outp + (((size_t)(n * C + co)) << 16) + hwbase + nt * 16;
#pragma unroll
      for (int r = 0; r < 4; ++r) op[(size_t)r << 16] = acc[r];
    }
  }
}

// ---------------------------------------------------------------------------
extern "C" void kernel_launch(void* const* d_in, const int* in_sizes, int n_in,
                              void* d_out, int out_size, void* d_ws, size_t ws_size,
                              hipStream_t stream) {
  const void* x = d_in[0];       // (8,64,256,256)   bf16 or fp32
  const void* qkv_w = d_in[1];   // (192,64,1,1)
  const void* dw_w = d_in[2];    // (192,1,3,3)
  const void* proj_w = d_in[3];  // (64,64,1,1)
  const void* temp = d_in[4];    // (64,1,1)

  // workspace layout:
  //   qkv1 bf16 [B,192,H,W]  : bytes [0, 201326592)
  //   voutb bf16 [B,64,H,W]  : bytes [201326592, 268435456)
  //   flag int               : byte 402653184 (kept at prior offset)
  u16* qkv1 = (u16*)d_ws;
  u16* voutb = qkv1 + (size_t)BATCH * C3 * HW;
  int* flag = (int*)((char*)d_ws + (size_t)2 * BATCH * C3 * HW * 2);
  float* outp = (float*)d_out;

  k0_det<<<1, 256, 0, stream>>>((const unsigned int*)x, flag);
  k1_mfma<<<NPIX / 256, 256, 0, stream>>>(x, qkv_w, qkv1, flag);
  k23_fused<<<BATCH * C * 32, 256, 0, stream>>>(qkv1, dw_w, temp, voutb, flag);
  k4_mfma<<<NPIX / 256, 256, 0, stream>>>(voutb, proj_w, outp, flag);
}

// Round 4
// 528.636 us; speedup vs baseline: 1.3000x; 1.0087x over previous
//
#include <hip/hip_runtime.h>
#include <hip/hip_bf16.h>
#include <stdint.h>

// Problem constants (fixed by the reference setup_inputs)
#define BATCH 8
#define C 64
#define C3 192
#define HW 65536            // 256*256
#define NPIX (BATCH * HW)   // 524288 pixels total

typedef unsigned short u16;

typedef __bf16 bf16x8 __attribute__((ext_vector_type(8)));
typedef float f32x4 __attribute__((ext_vector_type(4)));

union FragU {
  bf16x8 v;
  u16 u[8];
  uint4 q;
};

// bf16 (as raw u16) -> f32 : exact
__device__ __forceinline__ float bf2f(unsigned int u) {
  return __uint_as_float(u << 16);
}
// f32 -> bf16 raw bits, round-to-nearest-even
__device__ __forceinline__ u16 f2bf(float f) {
  unsigned int x = __float_as_uint(f);
  unsigned int r = (x + 0x7fffu + ((x >> 16) & 1u)) >> 16;
  return (u16)r;
}

__device__ __forceinline__ void unpack8(uint4 v, float* f) {
  f[0] = bf2f(v.x & 0xffffu); f[1] = bf2f(v.x >> 16);
  f[2] = bf2f(v.y & 0xffffu); f[3] = bf2f(v.y >> 16);
  f[4] = bf2f(v.z & 0xffffu); f[5] = bf2f(v.z >> 16);
  f[6] = bf2f(v.w & 0xffffu); f[7] = bf2f(v.w >> 16);
}

// ---------------------------------------------------------------------------
// K0: input-dtype sniffer (bf16 vs fp32).
// flag = 1 -> inputs are bf16 ; flag = 0 -> inputs are fp32.
// ---------------------------------------------------------------------------
__global__ void k0_det(const unsigned int* __restrict__ xbits,
                       int* __restrict__ flag) {
  __shared__ int cnt;
  if (threadIdx.x == 0) cnt = 0;
  __syncthreads();
  unsigned int u = xbits[threadIdx.x];
  int e = (u >> 7) & 0xff;  // exponent of low-half-as-bf16
  int pred = (e >= 96 && e <= 134) ? 1 : 0;
  atomicAdd(&cnt, pred);
  __syncthreads();
  if (threadIdx.x == 0) *flag = (cnt >= 128) ? 1 : 0;
}

// ---------------------------------------------------------------------------
// K1 (MFMA): 1x1 conv as GEMM  qkv1[co,px] = sum_ci W[co,ci] * x[ci,px].
// Block: 256 threads (4 waves), BN=256 px, BM=192, K=64. (unchanged)
// ---------------------------------------------------------------------------
__global__ __launch_bounds__(256) void k1_mfma(const void* __restrict__ xv,
                                               const void* __restrict__ wv,
                                               u16* __restrict__ qkv1,
                                               const int* __restrict__ flag) {
  const int isbf = *flag;  // uniform branch
  __shared__ u16 wl[C3 * C];  // 24576 B, swizzled bf16 weights
  for (int i = threadIdx.x; i < C3 * C; i += 256) {
    int row = i >> 6, col = i & 63;
    u16 b = isbf ? ((const u16*)wv)[i] : f2bf(((const float*)wv)[i]);
    int byt = row * 128 + ((col * 2) ^ ((row & 7) << 4));
    *(u16*)((char*)wl + byt) = b;
  }
  __syncthreads();

  const int w = threadIdx.x >> 6;
  const int l = threadIdx.x & 63;
  const int lg = l >> 4;   // lane group 0..3
  const int lr = l & 15;   // lane row/col 0..15
  const int n = blockIdx.x >> 8;                       // image index
  const int hwbase = ((blockIdx.x & 255) << 8) + w * 64 + lr;

  // ---- B fragments [nt][ks]: B[k][px], k = ks*32 + lg*8 + e, px = hwbase+nt*16
  FragU bfr[4][2];
  if (isbf) {
    const u16* xp = (const u16*)xv + (((size_t)n * C) << 16);
#pragma unroll
    for (int nt = 0; nt < 4; ++nt)
#pragma unroll
      for (int ks = 0; ks < 2; ++ks) {
        const u16* p = xp + (((size_t)(ks * 32 + lg * 8)) << 16) + hwbase + nt * 16;
#pragma unroll
        for (int e = 0; e < 8; ++e) bfr[nt][ks].u[e] = p[(size_t)e << 16];
      }
  } else {
    const float* xp = (const float*)xv + (((size_t)n * C) << 16);
#pragma unroll
    for (int nt = 0; nt < 4; ++nt)
#pragma unroll
      for (int ks = 0; ks < 2; ++ks) {
        const float* p = xp + (((size_t)(ks * 32 + lg * 8)) << 16) + hwbase + nt * 16;
#pragma unroll
        for (int e = 0; e < 8; ++e) bfr[nt][ks].u[e] = f2bf(p[(size_t)e << 16]);
      }
  }

  // ---- M-chunk loop: 48 output channels per chunk
#pragma unroll
  for (int mc = 0; mc < 4; ++mc) {
    bf16x8 af[3][2];
#pragma unroll
    for (int mt = 0; mt < 3; ++mt)
#pragma unroll
      for (int ks = 0; ks < 2; ++ks) {
        int row = mc * 48 + mt * 16 + lr;     // A row (co)
        int colb = ks * 64 + lg * 16;         // byte offset of k-slice
        FragU a;
        a.q = *(const uint4*)((const char*)wl + row * 128 +
                              (colb ^ ((row & 7) << 4)));
        af[mt][ks] = a.v;
      }
#pragma unroll
    for (int mt = 0; mt < 3; ++mt) {
#pragma unroll
      for (int nt = 0; nt < 4; ++nt) {
        f32x4 acc = {0.f, 0.f, 0.f, 0.f};
        acc = __builtin_amdgcn_mfma_f32_16x16x32_bf16(af[mt][0], bfr[nt][0].v,
                                                      acc, 0, 0, 0);
        acc = __builtin_amdgcn_mfma_f32_16x16x32_bf16(af[mt][1], bfr[nt][1].v,
                                                      acc, 0, 0, 0);
        int co = mc * 48 + mt * 16 + lg * 4;  // D row = lg*4 + r
        u16* op = qkv1 + (((size_t)(n * C3 + co)) << 16) + hwbase + nt * 16;
#pragma unroll
        for (int r = 0; r < 4; ++r) op[(size_t)r << 16] = f2bf(acc[r]);
      }
    }
  }
}

// ---------------------------------------------------------------------------
// K23 (fused): 3x3 depthwise conv + 8x8 patch circular-correlation attention.
// Block = one (n, c) channel-triple and an 8-row x 256-col strip (= exactly
// one patch row, 32 patches). 256 threads, 4 waves.
// v2: all phase-2/3 LDS traffic vectorized to b128; dw_s patch stride = 68 f32
// (16B-aligned, 68 mod 32 = 4 -> each quarter-wave's 4-dword windows tile the
// 32 banks at 2 accesses/bank = free). Phase-3 LDS instrs: 136 scalar -> 34
// b128 per thread.
// grid = 8*64*32 = 16384 blocks.
// ---------------------------------------------------------------------------
#define PSTR 68
__global__ __launch_bounds__(256) void k23_fused(const u16* __restrict__ qkv1,
                                                 const void* __restrict__ dwv,
                                                 const void* __restrict__ tv,
                                                 u16* __restrict__ voutb,
                                                 const int* __restrict__ flag) {
  const int isbf = *flag;
  const int strip = blockIdx.x & 31;
  const int c = (blockIdx.x >> 5) & 63;
  const int n = blockIdx.x >> 11;
  const int h0 = strip * 8;
  const int tid = threadIdx.x;

  __shared__ u16 in_s[3][10 * 256];       // 15360 B (bf16 staging, rows h0-1..h0+8)
  __shared__ float dw_s[3][32 * PSTR];    // 26112 B (f32 dw outputs, patch-major)

  // ---- Phase 1: stage (coalesced uint4 rows; zero for out-of-image rows)
  for (int idx = tid; idx < 3 * 10 * 32; idx += 256) {
    int pl = idx / 320;
    int rem = idx - pl * 320;
    int r = rem >> 5;        // staged row 0..9  (global row h0 + r - 1)
    int cg = rem & 31;       // col group of 8
    int gh = h0 + r - 1;
    uint4 val = make_uint4(0u, 0u, 0u, 0u);
    if (gh >= 0 && gh < 256) {
      const u16* src = qkv1 + (((size_t)(n * C3 + c + 64 * pl)) << 16) +
                       gh * 256 + cg * 8;
      val = *reinterpret_cast<const uint4*>(src);
    }
    *reinterpret_cast<uint4*>(&in_s[pl][r * 256 + cg * 8]) = val;
  }
  __syncthreads();

  // ---- Phase 2: depthwise conv. thread -> (row = tid>>5, patch = tid&31)
  const int row = tid >> 5;   // output row within strip, 0..7
  const int pch = tid & 31;   // patch index == col group of 8
  const int col0 = pch * 8;

  for (int pl = 0; pl < 3; ++pl) {
    int ch = c + 64 * pl;
    float wv9[9];
    if (isbf) {
      const u16* dw = (const u16*)dwv;
#pragma unroll
      for (int t = 0; t < 9; ++t) wv9[t] = bf2f(dw[ch * 9 + t]);
    } else {
      const float* dw = (const float*)dwv;
#pragma unroll
      for (int t = 0; t < 9; ++t) wv9[t] = dw[ch * 9 + t];
    }
    float acc[8];
#pragma unroll
    for (int j = 0; j < 8; ++j) acc[j] = 0.f;
    // input center row for output row i is staged row i+1 -> rows i..i+2
#pragma unroll
    for (int kh = 0; kh < 3; ++kh) {
      const u16* rp = &in_s[pl][(row + kh) * 256 + col0];
      uint4 rv = *reinterpret_cast<const uint4*>(rp);
      float r8[8];
      unpack8(rv, r8);
      float lft = (col0 > 0) ? bf2f(rp[-1]) : 0.f;
      float rgt = (col0 < 248) ? bf2f(rp[8]) : 0.f;
      float w0 = wv9[kh * 3], w1 = wv9[kh * 3 + 1], w2 = wv9[kh * 3 + 2];
      acc[0] += lft * w0 + r8[0] * w1 + r8[1] * w2;
#pragma unroll
      for (int j = 1; j < 7; ++j)
        acc[j] += r8[j - 1] * w0 + r8[j] * w1 + r8[j + 1] * w2;
      acc[7] += r8[6] * w0 + r8[7] * w1 + rgt * w2;
    }
    // vectorized b128 stores, conflict-free with PSTR=68
    *reinterpret_cast<float4*>(&dw_s[pl][pch * PSTR + row * 8]) =
        make_float4(acc[0], acc[1], acc[2], acc[3]);
    *reinterpret_cast<float4*>(&dw_s[pl][pch * PSTR + row * 8 + 4]) =
        make_float4(acc[4], acc[5], acc[6], acc[7]);
  }
  __syncthreads();

  // ---- Phase 3: 8x8 circular correlation, x temperature, x v
  const int s = row;  // this thread computes output row s of patch pch
  float acc8[8];
#pragma unroll
  for (int j = 0; j < 8; ++j) acc8[j] = 0.f;
  const float* qb = &dw_s[0][pch * PSTR];
  const float* kb = &dw_s[1][pch * PSTR];
#pragma unroll
  for (int a = 0; a < 8; ++a) {
    float4 q0 = *reinterpret_cast<const float4*>(qb + a * 8);
    float4 q1 = *reinterpret_cast<const float4*>(qb + a * 8 + 4);
    int kr = (s - a) & 7;          // runtime LDS row (addr math only)
    float4 k0 = *reinterpret_cast<const float4*>(kb + kr * 8);
    float4 k1 = *reinterpret_cast<const float4*>(kb + kr * 8 + 4);
    float qr[8] = {q0.x, q0.y, q0.z, q0.w, q1.x, q1.y, q1.z, q1.w};
    float kk[8] = {k0.x, k0.y, k0.z, k0.w, k1.x, k1.y, k1.z, k1.w};
#pragma unroll
    for (int b = 0; b < 8; ++b) {
      float qab = qr[b];
#pragma unroll
      for (int j = 0; j < 8; ++j) acc8[j] += qab * kk[(j - b) & 7];
    }
  }

  float tc = isbf ? bf2f(((const u16*)tv)[c]) : ((const float*)tv)[c];
  const float* vb = &dw_s[2][pch * PSTR + s * 8];
  float4 v0 = *reinterpret_cast<const float4*>(vb);
  float4 v1 = *reinterpret_cast<const float4*>(vb + 4);
  float vr[8] = {v0.x, v0.y, v0.z, v0.w, v1.x, v1.y, v1.z, v1.w};
  unsigned int pk[4];
#pragma unroll
  for (int jj = 0; jj < 4; ++jj) {
    u16 lo = f2bf(acc8[jj * 2] * tc * vr[jj * 2]);
    u16 hi = f2bf(acc8[jj * 2 + 1] * tc * vr[jj * 2 + 1]);
    pk[jj] = (unsigned int)lo | ((unsigned int)hi << 16);
  }
  *reinterpret_cast<uint4*>(voutb + (((size_t)(n * C + c)) << 16) +
                            (h0 + s) * 256 + pch * 8) =
      make_uint4(pk[0], pk[1], pk[2], pk[3]);
}

// ---------------------------------------------------------------------------
// K4 (MFMA): 1x1 proj conv as GEMM  out[co,px] = sum_ci Wp[co,ci]*vout[ci,px].
// vin is bf16 (written by K23). Output fp32. (unchanged)
// ---------------------------------------------------------------------------
__global__ __launch_bounds__(256) void k4_mfma(const u16* __restrict__ vin,
                                               const void* __restrict__ pwv,
                                               float* __restrict__ outp,
                                               const int* __restrict__ flag) {
  const int isbf = *flag;
  __shared__ u16 wl[C * C];  // 8192 B, swizzled bf16 weights
  for (int i = threadIdx.x; i < C * C; i += 256) {
    int row = i >> 6, col = i & 63;
    u16 b = isbf ? ((const u16*)pwv)[i] : f2bf(((const float*)pwv)[i]);
    *(u16*)((char*)wl + row * 128 + ((col * 2) ^ ((row & 7) << 4))) = b;
  }
  __syncthreads();

  const int w = threadIdx.x >> 6;
  const int l = threadIdx.x & 63;
  const int lg = l >> 4, lr = l & 15;
  const int n = blockIdx.x >> 8;
  const int hwbase = ((blockIdx.x & 255) << 8) + w * 64 + lr;

  const u16* xp = vin + (((size_t)n * C) << 16);
  FragU bfr[4][2];
#pragma unroll
  for (int nt = 0; nt < 4; ++nt)
#pragma unroll
    for (int ks = 0; ks < 2; ++ks) {
      const u16* p = xp + (((size_t)(ks * 32 + lg * 8)) << 16) + hwbase + nt * 16;
#pragma unroll
      for (int e = 0; e < 8; ++e) bfr[nt][ks].u[e] = p[(size_t)e << 16];
    }

#pragma unroll
  for (int mt = 0; mt < 4; ++mt) {
    bf16x8 af[2];
#pragma unroll
    for (int ks = 0; ks < 2; ++ks) {
      int row = mt * 16 + lr;
      int colb = ks * 64 + lg * 16;
      FragU a;
      a.q = *(const uint4*)((const char*)wl + row * 128 +
                            (colb ^ ((row & 7) << 4)));
      af[ks] = a.v;
    }
#pragma unroll
    for (int nt = 0; nt < 4; ++nt) {
      f32x4 acc = {0.f, 0.f, 0.f, 0.f};
      acc = __builtin_amdgcn_mfma_f32_16x16x32_bf16(af[0], bfr[nt][0].v, acc, 0, 0, 0);
      acc = __builtin_amdgcn_mfma_f32_16x16x32_bf16(af[1], bfr[nt][1].v, acc, 0, 0, 0);
      int co = mt * 16 + lg * 4;
      float* op = outp + (((size_t)(n * C + co)) << 16) + hwbase + nt * 16;
#pragma unroll
      for (int r = 0; r < 4; ++r) op[(size_t)r << 16] = acc[r];
    }
  }
}

// ---------------------------------------------------------------------------
extern "C" void kernel_launch(void* const* d_in, const int* in_sizes, int n_in,
                              void* d_out, int out_size, void* d_ws, size_t ws_size,
                              hipStream_t stream) {
  const void* x = d_in[0];       // (8,64,256,256)   bf16 or fp32
  const void* qkv_w = d_in[1];   // (192,64,1,1)
  const void* dw_w = d_in[2];    // (192,1,3,3)
  const void* proj_w = d_in[3];  // (64,64,1,1)
  const void* temp = d_in[4];    // (64,1,1)

  // workspace layout:
  //   qkv1 bf16 [B,192,H,W]  : bytes [0, 201326592)
  //   voutb bf16 [B,64,H,W]  : bytes [201326592, 268435456)
  //   flag int               : byte 402653184 (kept at prior offset)
  u16* qkv1 = (u16*)d_ws;
  u16* voutb = qkv1 + (size_t)BATCH * C3 * HW;
  int* flag = (int*)((char*)d_ws + (size_t)2 * BATCH * C3 * HW * 2);
  float* outp = (float*)d_out;

  k0_det<<<1, 256, 0, stream>>>((const unsigned int*)x, flag);
  k1_mfma<<<NPIX / 256, 256, 0, stream>>>(x, qkv_w, qkv1, flag);
  k23_fused<<<BATCH * C * 32, 256, 0, stream>>>(qkv1, dw_w, temp, voutb, flag);
  k4_mfma<<<NPIX / 256, 256, 0, stream>>>(voutb, proj_w, outp, flag);
}